// Round 17
// baseline (541.191 us; speedup 1.0000x reference)
//
#include <hip/hip_runtime.h>
#include <hip/hip_fp8.h>
#include <hip/hip_fp16.h>

#define BS 256
#define MAXIT 7
#define UNREACHED 0x3f3f3f3f
#define NR 256           // nodes per radix bucket (id>>8)
#define RB 256           // edge blocks for radix passes

// per-perm ctrl block (ints); perm pb uses ctrl + pb*1024
#define C_DONE  0
#define C_CNT   1
#define C_BLKA  2
#define C_BLKB  3
#define C_BLKC  4
#define C_NEWA  20  // per-level newly-claimed slots, 20..20+MAXIT-1
#define C_LOSS  32  // float (perm-0 block only)
#define C_V1    192 // float[64] (perm-0 block only)
#define C_V2    256 // float[64] (perm-0 block only)

typedef __hip_fp8_e4m3 fp8;

#define ALr(p)   __hip_atomic_load((p), __ATOMIC_RELAXED, __HIP_MEMORY_SCOPE_AGENT)
#define ALf(p)   __hip_atomic_load((p), __ATOMIC_RELAXED, __HIP_MEMORY_SCOPE_AGENT)
#define ASr(p,v) __hip_atomic_store((p),(v), __ATOMIC_RELAXED, __HIP_MEMORY_SCOPE_AGENT)
#define ASl(p,v) __hip_atomic_store((p),(v), __ATOMIC_RELEASE, __HIP_MEMORY_SCOPE_AGENT)

__device__ inline float softplusf(float x){
  return fmaxf(x, 0.f) + log1pf(expf(-fabsf(x)));
}

__device__ inline unsigned short h2us(__half h){
  union { __half h; unsigned short u; } c; c.h=h; return c.u;
}

// hstar/r from BFS level counts: hist[0]=1 (root), hist[h]=C_NEWA[h-1]
__device__ inline void cut_hr(const int* __restrict__ ctl, int target, int& hstar, int& r){
  int c=1;
  hstar=63; r=0;
  for(int h=1;h<=MAXIT;h++){
    int x=ctl[C_NEWA+h-1];
    if(c+x>target){ hstar=h; r=target-c; return; }
    c+=x;
  }
  r=target-c;
}

// ---------------- CSR build (in-edges, radix-partitioned) ----------------
__global__ void k_rhist(const int* __restrict__ dst, int E, int* __restrict__ hist,
                        int* __restrict__ bktBase, int nbk, int* __restrict__ ctrl){
  __shared__ int lh[512];
  int b=blockIdx.x, t=threadIdx.x;
  for(int i=t;i<nbk;i+=BS) lh[i]=0;
  __syncthreads();
  int per=(E+RB-1)/RB;
  int s0=b*per, s1=min(s0+per,E);
  for(int i=s0+t;i<s1;i+=BS) atomicAdd(&lh[dst[i]>>8],1);
  __syncthreads();
  for(int i=t;i<nbk;i+=BS) hist[i*RB+b]=lh[i];
  __shared__ int isLast;
  __syncthreads();
  if(t==0){
    __threadfence();
    isLast=(atomicAdd(&ctrl[C_BLKA],1)==(int)gridDim.x-1);
  }
  __syncthreads();
  if(!isLast) return;
  __threadfence();
  for(int r=t;r<nbk;r+=BS){
    const int* h=&hist[r*RB];
    int a=0;
    for(int bb=0;bb<RB;bb++) a+=ALr(&h[bb]);
    lh[r]=a;
  }
  __syncthreads();
  if(t==0){
    int acc=0;
    for(int r=0;r<nbk;r++){ bktBase[r]=acc; acc+=lh[r]; }
    bktBase[nbk]=E;
    ASr(&ctrl[C_BLKA],0);
    __threadfence();
  }
}

__global__ void k_cursors(const int* __restrict__ hist, const int* __restrict__ bktBase,
                          int* __restrict__ cursorTab, int nbk){
  __shared__ int s[BS];
  int r=blockIdx.x, t=threadIdx.x;
  if(r>=nbk) return;
  int v=hist[r*RB+t];
  s[t]=v; __syncthreads();
  for(int o=1;o<BS;o<<=1){
    int x=(t>=o)? s[t-o]:0;
    __syncthreads();
    if(t>=o) s[t]+=x;
    __syncthreads();
  }
  cursorTab[r*RB+t]=bktBase[r]+s[t]-v;
}

// pass 2: place packed (dstLow8,src) at private per-(block,bucket) cursors (32-bit pairs)
__global__ void k_rscatter(const int* __restrict__ dst, const int* __restrict__ src, int E,
                           const int* __restrict__ cursorTab,
                           unsigned* __restrict__ pairs, int nbk){
  __shared__ int cur[512];
  int b=blockIdx.x, t=threadIdx.x;
  for(int r=t;r<nbk;r+=BS) cur[r]=cursorTab[r*RB+b];
  __syncthreads();
  int per=(E+RB-1)/RB;
  int s0=b*per, s1=min(s0+per,E);
  for(int i=s0+t;i<s1;i+=BS){
    int d=dst[i], s=src[i];
    int pos=atomicAdd(&cur[d>>8],1);
    pairs[pos]=((unsigned)(d&255)<<24)|(unsigned)s;   // valid: N < 2^24
  }
}

// pass 3: per bucket: LDS degree count -> LDS scan -> rowptr window + place colD
__global__ void k_bplace2(const int* __restrict__ bktBase, const unsigned* __restrict__ pairs,
                          int* __restrict__ rowptr, int* __restrict__ colD, int N, int E){
  __shared__ int cnt[NR];
  __shared__ int s[NR];
  __shared__ int cur[NR];
  int b=blockIdx.x, t=threadIdx.x;
  int v0=b*NR, v1=min(v0+NR,N), nv=v1-v0;
  int s0=bktBase[b], e0=bktBase[b+1];
  cnt[t]=0;
  __syncthreads();
  for(int i=s0+t;i<e0;i+=BS){
    atomicAdd(&cnt[pairs[i]>>24],1);
  }
  __syncthreads();
  int v=(t<nv)?cnt[t]:0;
  s[t]=v; __syncthreads();
  for(int o=1;o<BS;o<<=1){
    int x=(t>=o)? s[t-o]:0;
    __syncthreads();
    if(t>=o) s[t]+=x;
    __syncthreads();
  }
  int excl=s[t]-v+s0;
  if(t<nv){ rowptr[v0+t]=excl; cur[t]=excl; }
  if(b==0&&t==0) rowptr[N]=E;
  __syncthreads();
  for(int i=s0+t;i<e0;i+=BS){
    unsigned pr=pairs[i];
    int pos=atomicAdd(&cur[pr>>24],1);
    colD[pos]=(int)(pr&0xFFFFFFu);
  }
}

// ---------------- FWI = [feat@W (fp8 64B) | permuted copy (64B)] per node ----------------
__global__ void k_fw(const float* __restrict__ feat, const float* __restrict__ W,
                     fp8* __restrict__ FWI, int N){
  __shared__ float sW[64*64];
  __shared__ float sf[4][64];
  int t=threadIdx.x;
  for(int i=t;i<64*64;i+=BS) sW[i]=W[i];
  __syncthreads();
  int j=t&63, r=t>>6;
  int ngroups=(N+3)>>2;
  for(int g=blockIdx.x; g<ngroups; g+=gridDim.x){
    int vr=g*4+r;
    sf[r][j] = (vr<N)? feat[vr*64+j] : 0.f;
    __syncthreads();
    if(vr<N){
      float acc=0.f;
      #pragma unroll
      for(int d=0;d<64;d++) acc += sf[r][d]*sW[d*64+j];
      FWI[(size_t)vr*128+j]=fp8(acc);
    }
    __syncthreads();
  }
}

__global__ void k_permrows(unsigned* __restrict__ FWI, const int* __restrict__ pn, int N){
  int i=blockIdx.x*BS+threadIdx.x, st=gridDim.x*BS;
  int tot=N*16;
  for(; i<tot; i+=st){
    int v=i>>4, e=i&15;
    FWI[(size_t)v*32+16+e]=FWI[(size_t)pn[v]*32+e];
  }
}

// ---------------- BFS init: interleaved hop12 + both ctrl blocks ----------------
__global__ void k_init2(int2* __restrict__ hop12, int N,
                        const int* __restrict__ perm1, const int* __restrict__ perm2,
                        int* __restrict__ ctrl,
                        unsigned* __restrict__ bits1, unsigned* __restrict__ bits2, int nw){
  int i=blockIdx.x*BS+threadIdx.x, st=gridDim.x*BS;
  int r1=perm1[0], r2=perm2[0];
  for(int v=i;v<N;v+=st){
    int2 h;
    h.x=(v==r1)?0:UNREACHED;
    h.y=(v==r2)?0:UNREACHED;
    hop12[v]=h;
  }
  for(int k=i;k<nw;k+=st){ bits1[k]=0u; bits2[k]=0u; }
  if(blockIdx.x==0&&threadIdx.x==0){
    for(int pb=0;pb<2;pb++){
      int* ctl=ctrl+pb*1024;
      ctl[C_DONE]=0; ctl[C_CNT]=1;
      ctl[C_BLKA]=0; ctl[C_BLKB]=0; ctl[C_BLKC]=0;
      for(int k=0;k<MAXIT;k++) ctl[C_NEWA+k]=0;
    }
    ((float*)ctrl)[C_LOSS]=0.f;
  }
}

// fused dual-perm pull over interleaved hop12: ONE 8B probe serves both perms
__global__ void k_pullF(const int* __restrict__ rowptr, const int* __restrict__ col,
                        int2* __restrict__ hop12,
                        const int* __restrict__ perm1, const int* __restrict__ perm2,
                        int* __restrict__ ctrl, int it, int N, int target){
  int t=threadIdx.x;
  int lvl=it+1;
  int* H=(int*)hop12;
  int done1=ALr(&ctrl[C_DONE]);
  int done2=ALr(&ctrl[1024+C_DONE]);
  if(done1&&done2) return;
  int bn1=0, bn2=0;
  for(int v=blockIdx.x*BS+t; v<N; v+=gridDim.x*BS){
    int2 hv=hop12[v];
    bool u1=(!done1)&&(hv.x==UNREACHED);
    bool u2=(!done2)&&(hv.y==UNREACHED);
    if(!(u1||u2)) continue;
    int b=rowptr[v], e=rowptr[v+1];
    for(int j=b;j<e;j++){
      int s=col[j];
      if(s==v) continue;                       // weight-0 self-loop
      int2 hs=hop12[s];
      if(u1 && hs.x==lvl-1){ H[2*v]=lvl;   bn1++; u1=false; }
      if(u2 && hs.y==lvl-1){ H[2*v+1]=lvl; bn2++; u2=false; }
      if(!(u1||u2)) break;
    }
  }
  __shared__ int sred[BS];
  __shared__ unsigned long long sk[BS];
  // ---- perm1 bookkeeping ----
  if(!done1){
    sred[t]=bn1; __syncthreads();
    for(int o=BS/2;o>0;o>>=1){ if(t<o) sred[t]+=sred[t+o]; __syncthreads(); }
    __shared__ int isLast1, totNew1;
    if(t==0){
      if(sred[0]) atomicAdd(&ctrl[C_NEWA+it], sred[0]);
      __threadfence();
      isLast1=(atomicAdd(&ctrl[C_BLKA],1)==(int)gridDim.x-1);
    }
    __syncthreads();
    if(isLast1){
      __threadfence();
      if(t==0) totNew1=ALr(&ctrl[C_NEWA+it]);
      __syncthreads();
      int newly=totNew1;
      __shared__ int seeded1;
      if(newly==0){
        unsigned long long key=~0ull;
        for(int v=t; v<N; v+=BS)
          if(ALr(&H[2*v])==UNREACHED){
            unsigned long long k=((unsigned long long)(unsigned)perm1[v]<<32)|(unsigned)v;
            if(k<key)key=k;
          }
        sk[t]=key; __syncthreads();
        for(int o=BS/2;o>0;o>>=1){ if(t<o&&sk[t+o]<sk[t])sk[t]=sk[t+o]; __syncthreads(); }
        if(t==0){
          seeded1=0;
          if(sk[0]!=~0ull){
            int idx=(int)(sk[0]&0xffffffffu);
            ASr(&H[2*idx],lvl);
            ctrl[C_NEWA+it]=1;
            seeded1=1;
          }
        }
        __syncthreads();
        newly=seeded1;
      }
      if(t==0){
        int c=ctrl[C_CNT]+newly;
        ctrl[C_CNT]=c;
        if(c>target) ASl(&ctrl[C_DONE],1);
        ASr(&ctrl[C_BLKA],0);
        __threadfence();
      }
    }
    __syncthreads();
  }
  // ---- perm2 bookkeeping ----
  if(!done2){
    int* ctl=ctrl+1024;
    sred[t]=bn2; __syncthreads();
    for(int o=BS/2;o>0;o>>=1){ if(t<o) sred[t]+=sred[t+o]; __syncthreads(); }
    __shared__ int isLast2, totNew2;
    if(t==0){
      if(sred[0]) atomicAdd(&ctl[C_NEWA+it], sred[0]);
      __threadfence();
      isLast2=(atomicAdd(&ctl[C_BLKA],1)==(int)gridDim.x-1);
    }
    __syncthreads();
    if(isLast2){
      __threadfence();
      if(t==0) totNew2=ALr(&ctl[C_NEWA+it]);
      __syncthreads();
      int newly=totNew2;
      __shared__ int seeded2;
      if(newly==0){
        unsigned long long key=~0ull;
        for(int v=t; v<N; v+=BS)
          if(ALr(&H[2*v+1])==UNREACHED){
            unsigned long long k=((unsigned long long)(unsigned)perm2[v]<<32)|(unsigned)v;
            if(k<key)key=k;
          }
        sk[t]=key; __syncthreads();
        for(int o=BS/2;o>0;o>>=1){ if(t<o&&sk[t+o]<sk[t])sk[t]=sk[t+o]; __syncthreads(); }
        if(t==0){
          seeded2=0;
          if(sk[0]!=~0ull){
            int idx=(int)(sk[0]&0xffffffffu);
            ASr(&H[2*idx+1],lvl);
            ctl[C_NEWA+it]=1;
            seeded2=1;
          }
        }
        __syncthreads();
        newly=seeded2;
      }
      if(t==0){
        int c=ctl[C_CNT]+newly;
        ctl[C_CNT]=c;
        if(c>target) ASl(&ctl[C_DONE],1);
        ASr(&ctl[C_BLKA],0);
        __threadfence();
      }
    }
  }
}

// flag bits + word-popcount scan, both perms per launch (ticket per half)
__global__ void k_flagscan2(const int2* __restrict__ hop12,
                            const int* __restrict__ perm1, const int* __restrict__ perm2,
                            unsigned* __restrict__ bits1, unsigned* __restrict__ bits2,
                            int* __restrict__ wordpref1, int* __restrict__ wordpref2,
                            int N, int nw, int* __restrict__ ctrl, int target, int NB){
  int pb = blockIdx.x>=NB;
  int lb = blockIdx.x - (pb?NB:0);
  const int* hopi = ((const int*)hop12) + pb;    // stride-2 view: .x or .y
  const int* perm = pb? perm2:perm1;
  unsigned* bits = pb? bits2:bits1;
  int* wordpref = pb? wordpref2:wordpref1;
  int* ctl = ctrl + pb*1024;
  int t=threadIdx.x;
  int hstar,rr; cut_hr(ctl,target,hstar,rr);
  for(int v=lb*BS+t; v<N; v+=NB*BS)
    if(min(hopi[2*v],63)==hstar){
      int p=perm[v];
      atomicOr(&bits[p>>5], 1u<<(p&31));
    }
  __shared__ int isLast;
  if(t==0){
    __threadfence();
    isLast=(atomicAdd(&ctl[C_BLKC],1)==NB-1);
  }
  __syncthreads();
  if(!isLast) return;
  __threadfence();
  __shared__ int ss[BS];
  __shared__ int carry;
  if(t==0) carry=0;
  __syncthreads();
  for(int base=0; base<nw; base+=BS){
    int i=base+t;
    int v=(i<nw)? __popc(ALr(&bits[i])) : 0;
    ss[t]=v; __syncthreads();
    for(int o=1;o<BS;o<<=1){
      int x=(t>=o)? ss[t-o]:0;
      __syncthreads();
      if(t>=o) ss[t]+=x;
      __syncthreads();
    }
    if(i<nw) wordpref[i]=carry+ss[t]-v;
    __syncthreads();
    if(t==0) carry+=ss[BS-1];
    __syncthreads();
  }
  if(t==0){ ASr(&ctl[C_BLKC],0); __threadfence(); }
}

// packed keep mask for both perms in one pass (one hop12 load per node)
__global__ void k_keep2(const int2* __restrict__ hop12,
                        const int* __restrict__ perm1, const int* __restrict__ perm2,
                        const unsigned* __restrict__ bits1, const unsigned* __restrict__ bits2,
                        const int* __restrict__ wordpref1, const int* __restrict__ wordpref2,
                        int* __restrict__ keepPk, int N, const int* __restrict__ ctrl, int target){
  int h1,r1,h2,r2;
  cut_hr(ctrl,target,h1,r1);
  cut_hr(ctrl+1024,target,h2,r2);
  int i=blockIdx.x*BS+threadIdx.x, st=gridDim.x*BS;
  for(int v=i;v<N;v+=st){
    int2 hv=hop12[v];
    int h=min(hv.x,63), kp1=0;
    if(h<h1) kp1=1;
    else if(h==h1){
      int p=perm1[v];
      unsigned mask=(2u<<(p&31))-1u;
      int cum=wordpref1[p>>5]+__popc(bits1[p>>5]&mask);
      kp1=(cum<=r1);
    }
    h=min(hv.y,63); int kp2=0;
    if(h<h2) kp2=1;
    else if(h==h2){
      int p=perm2[v];
      unsigned mask=(2u<<(p&31))-1u;
      int cum=wordpref2[p>>5]+__popc(bits2[p>>5]&mask);
      kp2=(cum<=r2);
    }
    keepPk[v]=kp1|(kp2<<1);
  }
}

// ---------------- fused mega gather over interleaved FWI (one 128B line per edge) ----------------
__global__ void __launch_bounds__(BS, 8) k_mega(
    const int* __restrict__ rowptr, const int* __restrict__ col,
    const unsigned char* __restrict__ FWI8, const int* __restrict__ keepPk,
    unsigned short* __restrict__ P, unsigned short* __restrict__ Q,
    float* __restrict__ sp1, float* __restrict__ sp2, int N){
  __shared__ uint4 lds4[4][8][8];              // [wave][edge][128B row]
  __shared__ float sh1[4][64], sh2[4][64];
  int t=threadIdx.x, lane=t&63, w=t>>6;
  int eidx=lane>>3, q=lane&7;
  int woff=lane>>2, bsh=(lane&3)*8;
  volatile unsigned* l32=(volatile unsigned*)&lds4[w][0][0];
  int wid=(blockIdx.x*BS+t)>>6, nw=(gridDim.x*BS)>>6;
  float acc1=0.f, acc2=0.f;
  for(int v=wid; v<N; v+=nw){
    int b=rowptr[v], e=rowptr[v+1];
    int deg=e-b;
    int kv=keepPk[v];
    float ap=0.f, an=0.f, a1=0.f, a2=0.f;
    int c1t=0, c2t=0;
    for(int c0=b; c0<e; c0+=8){
      int n=min(8, e-c0);
      uint4 wa=make_uint4(0,0,0,0);
      int kk=0;
      if(eidx<n){
        int s=__builtin_nontemporal_load(&col[c0+eidx]);   // read-once stream
        if(q==0) kk=keepPk[s];
        wa=*reinterpret_cast<const uint4*>(FWI8+((size_t)s<<7)+(q<<4));
      }
      lds4[w][eidx][q]=wa;
      __asm__ volatile("" ::: "memory");
      unsigned long long bal1=__ballot(q==0 && (kk&1));
      unsigned long long bal2=__ballot(q==0 && (kk&2));
      c1t+=__popcll(bal1); c2t+=__popcll(bal2);
      if(n==8){
        #pragma unroll
        for(int ee=0; ee<8; ee++){
          unsigned ua=l32[ee*32+woff];
          unsigned ub=l32[ee*32+16+woff];
          fp8 ha, hb;
          ha.__x=(unsigned char)(ua>>bsh);
          hb.__x=(unsigned char)(ub>>bsh);
          float fa=(float)ha, fb=(float)hb;
          ap+=fa; an+=fb;
          a1 += ((bal1>>(ee*8))&1) ? fa : 0.f;
          a2 += ((bal2>>(ee*8))&1) ? fa : 0.f;
        }
      } else {
        for(int ee=0; ee<n; ee++){
          unsigned ua=l32[ee*32+woff];
          unsigned ub=l32[ee*32+16+woff];
          fp8 ha, hb;
          ha.__x=(unsigned char)(ua>>bsh);
          hb.__x=(unsigned char)(ub>>bsh);
          float fa=(float)ha, fb=(float)hb;
          ap+=fa; an+=fb;
          a1 += ((bal1>>(ee*8))&1) ? fa : 0.f;
          a2 += ((bal2>>(ee*8))&1) ? fa : 0.f;
        }
      }
      __asm__ volatile("" ::: "memory");
    }
    float invd=1.f/(float)deg;
    float p =fmaxf(ap*invd, 0.f);
    float qq=fmaxf(an*invd, 0.f);
    __builtin_nontemporal_store(h2us(__float2half(p)),  &P[(size_t)v*64+lane]);  // write-once
    __builtin_nontemporal_store(h2us(__float2half(qq)), &Q[(size_t)v*64+lane]);
    if(kv&1) acc1+=fmaxf(a1/(float)max(c1t,1), 0.f);
    if(kv&2) acc2+=fmaxf(a2/(float)max(c2t,1), 0.f);
  }
  sh1[w][lane]=acc1; sh2[w][lane]=acc2;
  __syncthreads();
  if(w==0){
    sp1[blockIdx.x*64+lane]=sh1[0][lane]+sh1[1][lane]+sh1[2][lane]+sh1[3][lane];
    sp2[blockIdx.x*64+lane]=sh2[0][lane]+sh2[1][lane]+sh2[2][lane]+sh2[3][lane];
  }
}

// fused hierarchical reduce + sigmoid + W_disc matvec (ticket; last block finishes)
__global__ void k_redsum(const float* __restrict__ sp1, const float* __restrict__ sp2,
                         int nb, int rows, float* __restrict__ sp1b, float* __restrict__ sp2b,
                         const float* __restrict__ Wd, float* __restrict__ cf,
                         int* __restrict__ ctrl, float invk){
  __shared__ float s[BS];
  int t=threadIdx.x, lane=t&63, p=t>>6;
  int base=blockIdx.x*rows;
  float a=0.f;
  for(int r=p; r<rows; r+=4){ int row=base+r; if(row<nb) a+=sp1[row*64+lane]; }
  s[t]=a; __syncthreads();
  if(t<64) sp1b[blockIdx.x*64+t]=s[t]+s[t+64]+s[t+128]+s[t+192];
  __syncthreads();
  a=0.f;
  for(int r=p; r<rows; r+=4){ int row=base+r; if(row<nb) a+=sp2[row*64+lane]; }
  s[t]=a; __syncthreads();
  if(t<64) sp2b[blockIdx.x*64+t]=s[t]+s[t+64]+s[t+128]+s[t+192];
  __shared__ int isLast;
  __syncthreads();
  if(t==0){
    __threadfence();
    isLast=(atomicAdd(&ctrl[C_BLKB],1)==(int)gridDim.x-1);
  }
  __syncthreads();
  if(!isLast) return;
  __threadfence();
  int nb2=gridDim.x;
  __shared__ float sig[64];
  a=0.f;
  for(int b=p;b<nb2;b+=4) a+=ALf(&sp1b[b*64+lane]);
  s[t]=a; __syncthreads();
  if(t<64){
    float x=(s[t]+s[t+64]+s[t+128]+s[t+192])*invk;
    sig[t]=1.f/(1.f+expf(-x));
  }
  __syncthreads();
  if(t<64){
    float acc=0.f;
    #pragma unroll
    for(int d=0;d<64;d++) acc+=Wd[t*64+d]*sig[d];
    cf[C_V1+t]=acc;
  }
  __syncthreads();
  a=0.f;
  for(int b=p;b<nb2;b+=4) a+=ALf(&sp2b[b*64+lane]);
  s[t]=a; __syncthreads();
  if(t<64){
    float x=(s[t]+s[t+64]+s[t+128]+s[t+192])*invk;
    sig[t]=1.f/(1.f+expf(-x));
  }
  __syncthreads();
  if(t<64){
    float acc=0.f;
    #pragma unroll
    for(int d=0;d<64;d++) acc+=Wd[t*64+d]*sig[d];
    cf[C_V2+t]=acc;
  }
  if(t==0){ ASr(&ctrl[C_BLKB],0); __threadfence(); }
}

// streaming BCE loss over materialized P/Q + fused final write (ticket)
__global__ void k_loss2(const unsigned short* __restrict__ P, const unsigned short* __restrict__ Q,
                        float* __restrict__ cf, int* __restrict__ ctrl,
                        float* __restrict__ out, int N){
  __shared__ float sv1[64], sv2[64];
  __shared__ float sred[BS];
  int t=threadIdx.x;
  if(t<64){ sv1[t]=cf[C_V1+t]; sv2[t]=cf[C_V2+t]; }
  __syncthreads();
  int i=blockIdx.x*BS+t, st=gridDim.x*BS;
  float acc=0.f;
  for(int v=i; v<N; v+=st){
    const unsigned* pr=(const unsigned*)(P+(size_t)v*64);
    const unsigned* qr=(const unsigned*)(Q+(size_t)v*64);
    float a1=0.f,a2=0.f,b1=0.f,b2=0.f;
    #pragma unroll
    for(int j=0;j<32;j++){
      unsigned pu=__builtin_nontemporal_load(&pr[j]);
      unsigned qu=__builtin_nontemporal_load(&qr[j]);
      int d=j*2;
      __half2 ph=*(const __half2*)&pu;
      __half2 qh=*(const __half2*)&qu;
      float2 pf=__half22float2(ph);
      float2 qf=__half22float2(qh);
      a1=fmaf(pf.x,sv1[d],a1); a1=fmaf(pf.y,sv1[d+1],a1);
      a2=fmaf(pf.x,sv2[d],a2); a2=fmaf(pf.y,sv2[d+1],a2);
      b1=fmaf(qf.x,sv1[d],b1); b1=fmaf(qf.y,sv1[d+1],b1);
      b2=fmaf(qf.x,sv2[d],b2); b2=fmaf(qf.y,sv2[d+1],b2);
    }
    acc += softplusf(-a1)+softplusf(b1)+softplusf(-a2)+softplusf(b2);
  }
  sred[t]=acc;
  __syncthreads();
  for(int o=BS/2;o>0;o>>=1){ if(t<o) sred[t]+=sred[t+o]; __syncthreads(); }
  __shared__ int isLast;
  if(t==0){
    atomicAdd(&cf[C_LOSS], sred[0]);
    __threadfence();
    isLast=(atomicAdd(&ctrl[C_BLKC],1)==(int)gridDim.x-1);
  }
  __syncthreads();
  if(t==0 && isLast){
    __threadfence();
    out[0]=ALf(&cf[C_LOSS])/(float)N;
    ASr(&ctrl[C_BLKC],0);
  }
}

extern "C" void kernel_launch(void* const* d_in, const int* in_sizes, int n_in,
                              void* d_out, int out_size, void* d_ws, size_t ws_size,
                              hipStream_t stream) {
  const float* feat    = (const float*)d_in[0];
  const float* Wenc    = (const float*)d_in[1];
  const float* Wdisc   = (const float*)d_in[2];
  const int*   src     = (const int*)d_in[3];
  const int*   dst     = (const int*)d_in[4];
  const int*   permneg = (const int*)d_in[5];
  const int*   perm1   = (const int*)d_in[6];
  const int*   perm2   = (const int*)d_in[7];
  float* out = (float*)d_out;

  int N = in_sizes[5];
  int E = in_sizes[3];
  int target = (int)((double)N*0.8);
  int NB = (N+BS-1)/BS;
  int WORDS = (N+31)/32;
  int NBK = (N+NR-1)/NR;
  const int SUBB = 2048;
  const int R1B = 128, R1ROWS = SUBB/R1B;

  // workspace carve (256B-aligned chunks)
  char* w = (char*)d_ws;
  auto alloc = [&](size_t bytes)->void*{
    void* p = (void*)w;
    w += (bytes + 255) & ~(size_t)255;
    return p;
  };
  int*      ctrl     = (int*)     alloc(8192);
  int*      rowptrD  = (int*)     alloc((size_t)(N+1)*4);
  int*      histD    = (int*)     alloc((size_t)RB*NBK*4);
  int*      cursorTab= (int*)     alloc((size_t)RB*NBK*4);
  int*      bktBase  = (int*)     alloc((size_t)(NBK+1)*4);
  int*      colD     = (int*)     alloc((size_t)E*4);
  unsigned* pairs    = (unsigned*)alloc((size_t)E*4);
  int2*     hop12    = (int2*)    alloc((size_t)N*8);
  int*      keepPk   = (int*)     alloc((size_t)N*4);
  unsigned* bits1    = (unsigned*)alloc((size_t)WORDS*4);
  unsigned* bits2    = (unsigned*)alloc((size_t)WORDS*4);
  int*      wordpref1= (int*)     alloc((size_t)(WORDS+1)*4);
  int*      wordpref2= (int*)     alloc((size_t)(WORDS+1)*4);
  fp8*      FWI      = (fp8*)     alloc((size_t)N*128);
  unsigned short* P  = (unsigned short*)alloc((size_t)N*64*2);
  unsigned short* Q  = (unsigned short*)alloc((size_t)N*64*2);
  float*    sp1      = (float*)   alloc((size_t)SUBB*64*4);
  float*    sp2      = (float*)   alloc((size_t)SUBB*64*4);
  float*    sp1b     = (float*)   alloc((size_t)R1B*64*4);
  float*    sp2b     = (float*)   alloc((size_t)R1B*64*4);
  float*    cf = (float*)ctrl;

  (void)hipMemsetAsync(ctrl, 0, 8192, stream);

  // --- build in-CSR via radix partition (32-bit packed pairs) ---
  k_rhist   <<<RB,  BS, 0, stream>>>(dst, E, histD, bktBase, NBK, ctrl);
  k_cursors <<<NBK, BS, 0, stream>>>(histD, bktBase, cursorTab, NBK);
  k_rscatter<<<RB,  BS, 0, stream>>>(dst, src, E, cursorTab, pairs, NBK);
  k_bplace2 <<<NBK, BS, 0, stream>>>(bktBase, pairs, rowptrD, colD, N, E);

  // --- FWI = [feat@W | permuted] interleaved fp8 ---
  k_fw      <<<2048, BS, 0, stream>>>(feat, Wenc, FWI, N);
  k_permrows<<<4096, BS, 0, stream>>>((unsigned*)FWI, permneg, N);

  // --- both perms: fused dual-perm pull BFS (interleaved hop12) + keep mask ---
  k_init2<<<NB, BS, 0, stream>>>(hop12, N, perm1, perm2, ctrl, bits1, bits2, WORDS);
  for(int it=0; it<MAXIT; it++)
    k_pullF<<<NB, BS, 0, stream>>>(rowptrD, colD, hop12, perm1, perm2, ctrl, it, N, target);
  k_flagscan2<<<2*NB, BS, 0, stream>>>(hop12, perm1, perm2, bits1, bits2,
                                       wordpref1, wordpref2, N, WORDS, ctrl, target, NB);
  k_keep2    <<<2*NB, BS, 0, stream>>>(hop12, perm1, perm2, bits1, bits2,
                                       wordpref1, wordpref2, keepPk, N, ctrl, target);

  // --- fused gather: pos/neg rows + both subgraph summaries in one CSR pass ---
  k_mega  <<<SUBB, BS, 0, stream>>>(rowptrD, colD, (const unsigned char*)FWI, keepPk,
                                    P, Q, sp1, sp2, N);
  k_redsum<<<R1B, BS, 0, stream>>>(sp1, sp2, SUBB, R1ROWS, sp1b, sp2b, Wdisc, cf, ctrl,
                                   1.f/(float)target);

  // --- streaming loss + final ---
  k_loss2<<<NB, BS, 0, stream>>>(P, Q, cf, ctrl, out, N);
}

// Round 18
// 511.008 us; speedup vs baseline: 1.0591x; 1.0591x over previous
//
#include <hip/hip_runtime.h>
#include <hip/hip_fp8.h>
#include <hip/hip_fp16.h>

#define BS 256
#define MAXIT 7
#define UNREACHED 0x3f3f3f3f
#define NR 256           // nodes per radix bucket (id>>8)
#define RB 256           // edge blocks for radix passes

// per-perm ctrl block (ints); perm pb uses ctrl + pb*1024
#define C_DONE  0
#define C_CNT   1
#define C_BLKA  2
#define C_BLKB  3
#define C_BLKC  4
#define C_NEWA  20  // per-level newly-claimed slots, 20..20+MAXIT-1
#define C_LOSS  32  // float (perm-0 block only)
#define C_V1    192 // float[64] (perm-0 block only)
#define C_V2    256 // float[64] (perm-0 block only)

typedef __hip_fp8_e4m3 fp8;

#define ALr(p)   __hip_atomic_load((p), __ATOMIC_RELAXED, __HIP_MEMORY_SCOPE_AGENT)
#define ALf(p)   __hip_atomic_load((p), __ATOMIC_RELAXED, __HIP_MEMORY_SCOPE_AGENT)
#define ASr(p,v) __hip_atomic_store((p),(v), __ATOMIC_RELAXED, __HIP_MEMORY_SCOPE_AGENT)
#define ASl(p,v) __hip_atomic_store((p),(v), __ATOMIC_RELEASE, __HIP_MEMORY_SCOPE_AGENT)

__device__ inline float softplusf(float x){
  return fmaxf(x, 0.f) + log1pf(expf(-fabsf(x)));
}

__device__ inline unsigned short h2us(__half h){
  union { __half h; unsigned short u; } c; c.h=h; return c.u;
}

// hstar/r from BFS level counts: hist[0]=1 (root), hist[h]=C_NEWA[h-1]
__device__ inline void cut_hr(const int* __restrict__ ctl, int target, int& hstar, int& r){
  int c=1;
  hstar=63; r=0;
  for(int h=1;h<=MAXIT;h++){
    int x=ctl[C_NEWA+h-1];
    if(c+x>target){ hstar=h; r=target-c; return; }
    c+=x;
  }
  r=target-c;
}

// ---------------- CSR build (in-edges, radix-partitioned) ----------------
__global__ void k_rhist(const int* __restrict__ dst, int E, int* __restrict__ hist,
                        int* __restrict__ bktBase, int nbk, int* __restrict__ ctrl){
  __shared__ int lh[512];
  int b=blockIdx.x, t=threadIdx.x;
  for(int i=t;i<nbk;i+=BS) lh[i]=0;
  __syncthreads();
  int per=(E+RB-1)/RB;
  int s0=b*per, s1=min(s0+per,E);
  for(int i=s0+t;i<s1;i+=BS) atomicAdd(&lh[dst[i]>>8],1);
  __syncthreads();
  for(int i=t;i<nbk;i+=BS) hist[i*RB+b]=lh[i];
  __shared__ int isLast;
  __syncthreads();
  if(t==0){
    __threadfence();
    isLast=(atomicAdd(&ctrl[C_BLKA],1)==(int)gridDim.x-1);
  }
  __syncthreads();
  if(!isLast) return;
  __threadfence();
  for(int r=t;r<nbk;r+=BS){
    const int* h=&hist[r*RB];
    int a=0;
    for(int bb=0;bb<RB;bb++) a+=ALr(&h[bb]);
    lh[r]=a;
  }
  __syncthreads();
  if(t==0){
    int acc=0;
    for(int r=0;r<nbk;r++){ bktBase[r]=acc; acc+=lh[r]; }
    bktBase[nbk]=E;
    ASr(&ctrl[C_BLKA],0);
    __threadfence();
  }
}

__global__ void k_cursors(const int* __restrict__ hist, const int* __restrict__ bktBase,
                          int* __restrict__ cursorTab, int nbk){
  __shared__ int s[BS];
  int r=blockIdx.x, t=threadIdx.x;
  if(r>=nbk) return;
  int v=hist[r*RB+t];
  s[t]=v; __syncthreads();
  for(int o=1;o<BS;o<<=1){
    int x=(t>=o)? s[t-o]:0;
    __syncthreads();
    if(t>=o) s[t]+=x;
    __syncthreads();
  }
  cursorTab[r*RB+t]=bktBase[r]+s[t]-v;
}

// pass 2: place packed (dstLow8,src) at private per-(block,bucket) cursors (32-bit pairs)
__global__ void k_rscatter(const int* __restrict__ dst, const int* __restrict__ src, int E,
                           const int* __restrict__ cursorTab,
                           unsigned* __restrict__ pairs, int nbk){
  __shared__ int cur[512];
  int b=blockIdx.x, t=threadIdx.x;
  for(int r=t;r<nbk;r+=BS) cur[r]=cursorTab[r*RB+b];
  __syncthreads();
  int per=(E+RB-1)/RB;
  int s0=b*per, s1=min(s0+per,E);
  for(int i=s0+t;i<s1;i+=BS){
    int d=dst[i], s=src[i];
    int pos=atomicAdd(&cur[d>>8],1);
    pairs[pos]=((unsigned)(d&255)<<24)|(unsigned)s;   // valid: N < 2^24
  }
}

// pass 3: per bucket: LDS degree count -> LDS scan -> rowptr window + place colD
__global__ void k_bplace2(const int* __restrict__ bktBase, const unsigned* __restrict__ pairs,
                          int* __restrict__ rowptr, int* __restrict__ colD, int N, int E){
  __shared__ int cnt[NR];
  __shared__ int s[NR];
  __shared__ int cur[NR];
  int b=blockIdx.x, t=threadIdx.x;
  int v0=b*NR, v1=min(v0+NR,N), nv=v1-v0;
  int s0=bktBase[b], e0=bktBase[b+1];
  cnt[t]=0;
  __syncthreads();
  for(int i=s0+t;i<e0;i+=BS){
    atomicAdd(&cnt[pairs[i]>>24],1);
  }
  __syncthreads();
  int v=(t<nv)?cnt[t]:0;
  s[t]=v; __syncthreads();
  for(int o=1;o<BS;o<<=1){
    int x=(t>=o)? s[t-o]:0;
    __syncthreads();
    if(t>=o) s[t]+=x;
    __syncthreads();
  }
  int excl=s[t]-v+s0;
  if(t<nv){ rowptr[v0+t]=excl; cur[t]=excl; }
  if(b==0&&t==0) rowptr[N]=E;
  __syncthreads();
  for(int i=s0+t;i<e0;i+=BS){
    unsigned pr=pairs[i];
    int pos=atomicAdd(&cur[pr>>24],1);
    colD[pos]=(int)(pr&0xFFFFFFu);
  }
}

// ---------------- FWI = [feat@W (fp8 64B) | permuted copy (64B)] per node ----------------
__global__ void k_fw(const float* __restrict__ feat, const float* __restrict__ W,
                     fp8* __restrict__ FWI, int N){
  __shared__ float sW[64*64];
  __shared__ float sf[4][64];
  int t=threadIdx.x;
  for(int i=t;i<64*64;i+=BS) sW[i]=W[i];
  __syncthreads();
  int j=t&63, r=t>>6;
  int ngroups=(N+3)>>2;
  for(int g=blockIdx.x; g<ngroups; g+=gridDim.x){
    int vr=g*4+r;
    sf[r][j] = (vr<N)? feat[vr*64+j] : 0.f;
    __syncthreads();
    if(vr<N){
      float acc=0.f;
      #pragma unroll
      for(int d=0;d<64;d++) acc += sf[r][d]*sW[d*64+j];
      FWI[(size_t)vr*128+j]=fp8(acc);
    }
    __syncthreads();
  }
}

__global__ void k_permrows(unsigned* __restrict__ FWI, const int* __restrict__ pn, int N){
  int i=blockIdx.x*BS+threadIdx.x, st=gridDim.x*BS;
  int tot=N*16;
  for(; i<tot; i+=st){
    int v=i>>4, e=i&15;
    FWI[(size_t)v*32+16+e]=FWI[(size_t)pn[v]*32+e];
  }
}

// ---------------- BFS init: interleaved hop12 + both ctrl blocks ----------------
__global__ void k_init2(int2* __restrict__ hop12, int N,
                        const int* __restrict__ perm1, const int* __restrict__ perm2,
                        int* __restrict__ ctrl,
                        unsigned* __restrict__ bits1, unsigned* __restrict__ bits2, int nw){
  int i=blockIdx.x*BS+threadIdx.x, st=gridDim.x*BS;
  int r1=perm1[0], r2=perm2[0];
  for(int v=i;v<N;v+=st){
    int2 h;
    h.x=(v==r1)?0:UNREACHED;
    h.y=(v==r2)?0:UNREACHED;
    hop12[v]=h;
  }
  for(int k=i;k<nw;k+=st){ bits1[k]=0u; bits2[k]=0u; }
  if(blockIdx.x==0&&threadIdx.x==0){
    for(int pb=0;pb<2;pb++){
      int* ctl=ctrl+pb*1024;
      ctl[C_DONE]=0; ctl[C_CNT]=1;
      ctl[C_BLKA]=0; ctl[C_BLKB]=0; ctl[C_BLKC]=0;
      for(int k=0;k<MAXIT;k++) ctl[C_NEWA+k]=0;
    }
    ((float*)ctrl)[C_LOSS]=0.f;
  }
}

// fused dual-perm pull over interleaved hop12: ONE 8B probe serves both perms
__global__ void k_pullF(const int* __restrict__ rowptr, const int* __restrict__ col,
                        int2* __restrict__ hop12,
                        const int* __restrict__ perm1, const int* __restrict__ perm2,
                        int* __restrict__ ctrl, int it, int N, int target){
  int t=threadIdx.x;
  int lvl=it+1;
  int* H=(int*)hop12;
  int done1=ALr(&ctrl[C_DONE]);
  int done2=ALr(&ctrl[1024+C_DONE]);
  if(done1&&done2) return;
  int bn1=0, bn2=0;
  for(int v=blockIdx.x*BS+t; v<N; v+=gridDim.x*BS){
    int2 hv=hop12[v];
    bool u1=(!done1)&&(hv.x==UNREACHED);
    bool u2=(!done2)&&(hv.y==UNREACHED);
    if(!(u1||u2)) continue;
    int b=rowptr[v], e=rowptr[v+1];
    for(int j=b;j<e;j++){
      int s=col[j];
      if(s==v) continue;                       // weight-0 self-loop
      int2 hs=hop12[s];
      if(u1 && hs.x==lvl-1){ H[2*v]=lvl;   bn1++; u1=false; }
      if(u2 && hs.y==lvl-1){ H[2*v+1]=lvl; bn2++; u2=false; }
      if(!(u1||u2)) break;
    }
  }
  __shared__ int sred[BS];
  __shared__ unsigned long long sk[BS];
  // ---- perm1 bookkeeping ----
  if(!done1){
    sred[t]=bn1; __syncthreads();
    for(int o=BS/2;o>0;o>>=1){ if(t<o) sred[t]+=sred[t+o]; __syncthreads(); }
    __shared__ int isLast1, totNew1;
    if(t==0){
      if(sred[0]) atomicAdd(&ctrl[C_NEWA+it], sred[0]);
      __threadfence();
      isLast1=(atomicAdd(&ctrl[C_BLKA],1)==(int)gridDim.x-1);
    }
    __syncthreads();
    if(isLast1){
      __threadfence();
      if(t==0) totNew1=ALr(&ctrl[C_NEWA+it]);
      __syncthreads();
      int newly=totNew1;
      __shared__ int seeded1;
      if(newly==0){
        unsigned long long key=~0ull;
        for(int v=t; v<N; v+=BS)
          if(ALr(&H[2*v])==UNREACHED){
            unsigned long long k=((unsigned long long)(unsigned)perm1[v]<<32)|(unsigned)v;
            if(k<key)key=k;
          }
        sk[t]=key; __syncthreads();
        for(int o=BS/2;o>0;o>>=1){ if(t<o&&sk[t+o]<sk[t])sk[t]=sk[t+o]; __syncthreads(); }
        if(t==0){
          seeded1=0;
          if(sk[0]!=~0ull){
            int idx=(int)(sk[0]&0xffffffffu);
            ASr(&H[2*idx],lvl);
            ctrl[C_NEWA+it]=1;
            seeded1=1;
          }
        }
        __syncthreads();
        newly=seeded1;
      }
      if(t==0){
        int c=ctrl[C_CNT]+newly;
        ctrl[C_CNT]=c;
        if(c>target) ASl(&ctrl[C_DONE],1);
        ASr(&ctrl[C_BLKA],0);
        __threadfence();
      }
    }
    __syncthreads();
  }
  // ---- perm2 bookkeeping ----
  if(!done2){
    int* ctl=ctrl+1024;
    sred[t]=bn2; __syncthreads();
    for(int o=BS/2;o>0;o>>=1){ if(t<o) sred[t]+=sred[t+o]; __syncthreads(); }
    __shared__ int isLast2, totNew2;
    if(t==0){
      if(sred[0]) atomicAdd(&ctl[C_NEWA+it], sred[0]);
      __threadfence();
      isLast2=(atomicAdd(&ctl[C_BLKA],1)==(int)gridDim.x-1);
    }
    __syncthreads();
    if(isLast2){
      __threadfence();
      if(t==0) totNew2=ALr(&ctl[C_NEWA+it]);
      __syncthreads();
      int newly=totNew2;
      __shared__ int seeded2;
      if(newly==0){
        unsigned long long key=~0ull;
        for(int v=t; v<N; v+=BS)
          if(ALr(&H[2*v+1])==UNREACHED){
            unsigned long long k=((unsigned long long)(unsigned)perm2[v]<<32)|(unsigned)v;
            if(k<key)key=k;
          }
        sk[t]=key; __syncthreads();
        for(int o=BS/2;o>0;o>>=1){ if(t<o&&sk[t+o]<sk[t])sk[t]=sk[t+o]; __syncthreads(); }
        if(t==0){
          seeded2=0;
          if(sk[0]!=~0ull){
            int idx=(int)(sk[0]&0xffffffffu);
            ASr(&H[2*idx+1],lvl);
            ctl[C_NEWA+it]=1;
            seeded2=1;
          }
        }
        __syncthreads();
        newly=seeded2;
      }
      if(t==0){
        int c=ctl[C_CNT]+newly;
        ctl[C_CNT]=c;
        if(c>target) ASl(&ctl[C_DONE],1);
        ASr(&ctl[C_BLKA],0);
        __threadfence();
      }
    }
  }
}

// flag bits + word-popcount scan, both perms per launch (ticket per half)
__global__ void k_flagscan2(const int2* __restrict__ hop12,
                            const int* __restrict__ perm1, const int* __restrict__ perm2,
                            unsigned* __restrict__ bits1, unsigned* __restrict__ bits2,
                            int* __restrict__ wordpref1, int* __restrict__ wordpref2,
                            int N, int nw, int* __restrict__ ctrl, int target, int NB){
  int pb = blockIdx.x>=NB;
  int lb = blockIdx.x - (pb?NB:0);
  const int* hopi = ((const int*)hop12) + pb;    // stride-2 view: .x or .y
  const int* perm = pb? perm2:perm1;
  unsigned* bits = pb? bits2:bits1;
  int* wordpref = pb? wordpref2:wordpref1;
  int* ctl = ctrl + pb*1024;
  int t=threadIdx.x;
  int hstar,rr; cut_hr(ctl,target,hstar,rr);
  for(int v=lb*BS+t; v<N; v+=NB*BS)
    if(min(hopi[2*v],63)==hstar){
      int p=perm[v];
      atomicOr(&bits[p>>5], 1u<<(p&31));
    }
  __shared__ int isLast;
  if(t==0){
    __threadfence();
    isLast=(atomicAdd(&ctl[C_BLKC],1)==NB-1);
  }
  __syncthreads();
  if(!isLast) return;
  __threadfence();
  __shared__ int ss[BS];
  __shared__ int carry;
  if(t==0) carry=0;
  __syncthreads();
  for(int base=0; base<nw; base+=BS){
    int i=base+t;
    int v=(i<nw)? __popc(ALr(&bits[i])) : 0;
    ss[t]=v; __syncthreads();
    for(int o=1;o<BS;o<<=1){
      int x=(t>=o)? ss[t-o]:0;
      __syncthreads();
      if(t>=o) ss[t]+=x;
      __syncthreads();
    }
    if(i<nw) wordpref[i]=carry+ss[t]-v;
    __syncthreads();
    if(t==0) carry+=ss[BS-1];
    __syncthreads();
  }
  if(t==0){ ASr(&ctl[C_BLKC],0); __threadfence(); }
}

// packed keep mask for both perms in one pass (one hop12 load per node)
__global__ void k_keep2(const int2* __restrict__ hop12,
                        const int* __restrict__ perm1, const int* __restrict__ perm2,
                        const unsigned* __restrict__ bits1, const unsigned* __restrict__ bits2,
                        const int* __restrict__ wordpref1, const int* __restrict__ wordpref2,
                        int* __restrict__ keepPk, int N, const int* __restrict__ ctrl, int target){
  int h1,r1,h2,r2;
  cut_hr(ctrl,target,h1,r1);
  cut_hr(ctrl+1024,target,h2,r2);
  int i=blockIdx.x*BS+threadIdx.x, st=gridDim.x*BS;
  for(int v=i;v<N;v+=st){
    int2 hv=hop12[v];
    int h=min(hv.x,63), kp1=0;
    if(h<h1) kp1=1;
    else if(h==h1){
      int p=perm1[v];
      unsigned mask=(2u<<(p&31))-1u;
      int cum=wordpref1[p>>5]+__popc(bits1[p>>5]&mask);
      kp1=(cum<=r1);
    }
    h=min(hv.y,63); int kp2=0;
    if(h<h2) kp2=1;
    else if(h==h2){
      int p=perm2[v];
      unsigned mask=(2u<<(p&31))-1u;
      int cum=wordpref2[p>>5]+__popc(bits2[p>>5]&mask);
      kp2=(cum<=r2);
    }
    keepPk[v]=kp1|(kp2<<1);
  }
}

// ---------------- fused mega gather over interleaved FWI (one 128B line per edge) ----------------
__global__ void __launch_bounds__(BS, 8) k_mega(
    const int* __restrict__ rowptr, const int* __restrict__ col,
    const unsigned char* __restrict__ FWI8, const int* __restrict__ keepPk,
    unsigned short* __restrict__ P, unsigned short* __restrict__ Q,
    float* __restrict__ sp1, float* __restrict__ sp2, int N){
  __shared__ uint4 lds4[4][8][8];              // [wave][edge][128B row]
  __shared__ float sh1[4][64], sh2[4][64];
  int t=threadIdx.x, lane=t&63, w=t>>6;
  int eidx=lane>>3, q=lane&7;
  int woff=lane>>2, bsh=(lane&3)*8;
  volatile unsigned* l32=(volatile unsigned*)&lds4[w][0][0];
  int wid=(blockIdx.x*BS+t)>>6, nw=(gridDim.x*BS)>>6;
  float acc1=0.f, acc2=0.f;
  for(int v=wid; v<N; v+=nw){
    int b=rowptr[v], e=rowptr[v+1];
    int deg=e-b;
    int kv=keepPk[v];
    float ap=0.f, an=0.f, a1=0.f, a2=0.f;
    int c1t=0, c2t=0;
    for(int c0=b; c0<e; c0+=8){
      int n=min(8, e-c0);
      uint4 wa=make_uint4(0,0,0,0);
      int kk=0;
      if(eidx<n){
        int s=col[c0+eidx];
        if(q==0) kk=keepPk[s];
        wa=*reinterpret_cast<const uint4*>(FWI8+((size_t)s<<7)+(q<<4));
      }
      lds4[w][eidx][q]=wa;
      __asm__ volatile("" ::: "memory");
      unsigned long long bal1=__ballot(q==0 && (kk&1));
      unsigned long long bal2=__ballot(q==0 && (kk&2));
      c1t+=__popcll(bal1); c2t+=__popcll(bal2);
      if(n==8){
        #pragma unroll
        for(int ee=0; ee<8; ee++){
          unsigned ua=l32[ee*32+woff];
          unsigned ub=l32[ee*32+16+woff];
          fp8 ha, hb;
          ha.__x=(unsigned char)(ua>>bsh);
          hb.__x=(unsigned char)(ub>>bsh);
          float fa=(float)ha, fb=(float)hb;
          ap+=fa; an+=fb;
          a1 += ((bal1>>(ee*8))&1) ? fa : 0.f;
          a2 += ((bal2>>(ee*8))&1) ? fa : 0.f;
        }
      } else {
        for(int ee=0; ee<n; ee++){
          unsigned ua=l32[ee*32+woff];
          unsigned ub=l32[ee*32+16+woff];
          fp8 ha, hb;
          ha.__x=(unsigned char)(ua>>bsh);
          hb.__x=(unsigned char)(ub>>bsh);
          float fa=(float)ha, fb=(float)hb;
          ap+=fa; an+=fb;
          a1 += ((bal1>>(ee*8))&1) ? fa : 0.f;
          a2 += ((bal2>>(ee*8))&1) ? fa : 0.f;
        }
      }
      __asm__ volatile("" ::: "memory");
    }
    float invd=1.f/(float)deg;
    float p =fmaxf(ap*invd, 0.f);
    float qq=fmaxf(an*invd, 0.f);
    P[(size_t)v*64+lane]=h2us(__float2half(p));
    Q[(size_t)v*64+lane]=h2us(__float2half(qq));
    if(kv&1) acc1+=fmaxf(a1/(float)max(c1t,1), 0.f);
    if(kv&2) acc2+=fmaxf(a2/(float)max(c2t,1), 0.f);
  }
  sh1[w][lane]=acc1; sh2[w][lane]=acc2;
  __syncthreads();
  if(w==0){
    sp1[blockIdx.x*64+lane]=sh1[0][lane]+sh1[1][lane]+sh1[2][lane]+sh1[3][lane];
    sp2[blockIdx.x*64+lane]=sh2[0][lane]+sh2[1][lane]+sh2[2][lane]+sh2[3][lane];
  }
}

// fused hierarchical reduce + sigmoid + W_disc matvec (ticket; last block finishes)
__global__ void k_redsum(const float* __restrict__ sp1, const float* __restrict__ sp2,
                         int nb, int rows, float* __restrict__ sp1b, float* __restrict__ sp2b,
                         const float* __restrict__ Wd, float* __restrict__ cf,
                         int* __restrict__ ctrl, float invk){
  __shared__ float s[BS];
  int t=threadIdx.x, lane=t&63, p=t>>6;
  int base=blockIdx.x*rows;
  float a=0.f;
  for(int r=p; r<rows; r+=4){ int row=base+r; if(row<nb) a+=sp1[row*64+lane]; }
  s[t]=a; __syncthreads();
  if(t<64) sp1b[blockIdx.x*64+t]=s[t]+s[t+64]+s[t+128]+s[t+192];
  __syncthreads();
  a=0.f;
  for(int r=p; r<rows; r+=4){ int row=base+r; if(row<nb) a+=sp2[row*64+lane]; }
  s[t]=a; __syncthreads();
  if(t<64) sp2b[blockIdx.x*64+t]=s[t]+s[t+64]+s[t+128]+s[t+192];
  __shared__ int isLast;
  __syncthreads();
  if(t==0){
    __threadfence();
    isLast=(atomicAdd(&ctrl[C_BLKB],1)==(int)gridDim.x-1);
  }
  __syncthreads();
  if(!isLast) return;
  __threadfence();
  int nb2=gridDim.x;
  __shared__ float sig[64];
  a=0.f;
  for(int b=p;b<nb2;b+=4) a+=ALf(&sp1b[b*64+lane]);
  s[t]=a; __syncthreads();
  if(t<64){
    float x=(s[t]+s[t+64]+s[t+128]+s[t+192])*invk;
    sig[t]=1.f/(1.f+expf(-x));
  }
  __syncthreads();
  if(t<64){
    float acc=0.f;
    #pragma unroll
    for(int d=0;d<64;d++) acc+=Wd[t*64+d]*sig[d];
    cf[C_V1+t]=acc;
  }
  __syncthreads();
  a=0.f;
  for(int b=p;b<nb2;b+=4) a+=ALf(&sp2b[b*64+lane]);
  s[t]=a; __syncthreads();
  if(t<64){
    float x=(s[t]+s[t+64]+s[t+128]+s[t+192])*invk;
    sig[t]=1.f/(1.f+expf(-x));
  }
  __syncthreads();
  if(t<64){
    float acc=0.f;
    #pragma unroll
    for(int d=0;d<64;d++) acc+=Wd[t*64+d]*sig[d];
    cf[C_V2+t]=acc;
  }
  if(t==0){ ASr(&ctrl[C_BLKB],0); __threadfence(); }
}

// streaming BCE loss over materialized P/Q + fused final write (ticket)
__global__ void k_loss2(const unsigned short* __restrict__ P, const unsigned short* __restrict__ Q,
                        float* __restrict__ cf, int* __restrict__ ctrl,
                        float* __restrict__ out, int N){
  __shared__ float sv1[64], sv2[64];
  __shared__ float sred[BS];
  int t=threadIdx.x;
  if(t<64){ sv1[t]=cf[C_V1+t]; sv2[t]=cf[C_V2+t]; }
  __syncthreads();
  int i=blockIdx.x*BS+t, st=gridDim.x*BS;
  float acc=0.f;
  for(int v=i; v<N; v+=st){
    const uint4* pr=(const uint4*)(P+(size_t)v*64);
    const uint4* qr=(const uint4*)(Q+(size_t)v*64);
    float a1=0.f,a2=0.f,b1=0.f,b2=0.f;
    #pragma unroll
    for(int c=0;c<8;c++){
      uint4 pu=pr[c], qu=qr[c];
      unsigned arr[4]={pu.x,pu.y,pu.z,pu.w};
      unsigned brr[4]={qu.x,qu.y,qu.z,qu.w};
      #pragma unroll
      for(int j=0;j<4;j++){
        int d=c*8+j*2;
        __half2 ph=*(const __half2*)&arr[j];
        __half2 qh=*(const __half2*)&brr[j];
        float2 pf=__half22float2(ph);
        float2 qf=__half22float2(qh);
        a1=fmaf(pf.x,sv1[d],a1); a1=fmaf(pf.y,sv1[d+1],a1);
        a2=fmaf(pf.x,sv2[d],a2); a2=fmaf(pf.y,sv2[d+1],a2);
        b1=fmaf(qf.x,sv1[d],b1); b1=fmaf(qf.y,sv1[d+1],b1);
        b2=fmaf(qf.x,sv2[d],b2); b2=fmaf(qf.y,sv2[d+1],b2);
      }
    }
    acc += softplusf(-a1)+softplusf(b1)+softplusf(-a2)+softplusf(b2);
  }
  sred[t]=acc;
  __syncthreads();
  for(int o=BS/2;o>0;o>>=1){ if(t<o) sred[t]+=sred[t+o]; __syncthreads(); }
  __shared__ int isLast;
  if(t==0){
    atomicAdd(&cf[C_LOSS], sred[0]);
    __threadfence();
    isLast=(atomicAdd(&ctrl[C_BLKC],1)==(int)gridDim.x-1);
  }
  __syncthreads();
  if(t==0 && isLast){
    __threadfence();
    out[0]=ALf(&cf[C_LOSS])/(float)N;
    ASr(&ctrl[C_BLKC],0);
  }
}

extern "C" void kernel_launch(void* const* d_in, const int* in_sizes, int n_in,
                              void* d_out, int out_size, void* d_ws, size_t ws_size,
                              hipStream_t stream) {
  const float* feat    = (const float*)d_in[0];
  const float* Wenc    = (const float*)d_in[1];
  const float* Wdisc   = (const float*)d_in[2];
  const int*   src     = (const int*)d_in[3];
  const int*   dst     = (const int*)d_in[4];
  const int*   permneg = (const int*)d_in[5];
  const int*   perm1   = (const int*)d_in[6];
  const int*   perm2   = (const int*)d_in[7];
  float* out = (float*)d_out;

  int N = in_sizes[5];
  int E = in_sizes[3];
  int target = (int)((double)N*0.8);
  int NB = (N+BS-1)/BS;
  int WORDS = (N+31)/32;
  int NBK = (N+NR-1)/NR;
  const int SUBB = 2048;
  const int R1B = 128, R1ROWS = SUBB/R1B;

  // workspace carve (256B-aligned chunks)
  char* w = (char*)d_ws;
  auto alloc = [&](size_t bytes)->void*{
    void* p = (void*)w;
    w += (bytes + 255) & ~(size_t)255;
    return p;
  };
  int*      ctrl     = (int*)     alloc(8192);
  int*      rowptrD  = (int*)     alloc((size_t)(N+1)*4);
  int*      histD    = (int*)     alloc((size_t)RB*NBK*4);
  int*      cursorTab= (int*)     alloc((size_t)RB*NBK*4);
  int*      bktBase  = (int*)     alloc((size_t)(NBK+1)*4);
  int*      colD     = (int*)     alloc((size_t)E*4);
  unsigned* pairs    = (unsigned*)alloc((size_t)E*4);
  int2*     hop12    = (int2*)    alloc((size_t)N*8);
  int*      keepPk   = (int*)     alloc((size_t)N*4);
  unsigned* bits1    = (unsigned*)alloc((size_t)WORDS*4);
  unsigned* bits2    = (unsigned*)alloc((size_t)WORDS*4);
  int*      wordpref1= (int*)     alloc((size_t)(WORDS+1)*4);
  int*      wordpref2= (int*)     alloc((size_t)(WORDS+1)*4);
  fp8*      FWI      = (fp8*)     alloc((size_t)N*128);
  unsigned short* P  = (unsigned short*)alloc((size_t)N*64*2);
  unsigned short* Q  = (unsigned short*)alloc((size_t)N*64*2);
  float*    sp1      = (float*)   alloc((size_t)SUBB*64*4);
  float*    sp2      = (float*)   alloc((size_t)SUBB*64*4);
  float*    sp1b     = (float*)   alloc((size_t)R1B*64*4);
  float*    sp2b     = (float*)   alloc((size_t)R1B*64*4);
  float*    cf = (float*)ctrl;

  (void)hipMemsetAsync(ctrl, 0, 8192, stream);

  // --- build in-CSR via radix partition (32-bit packed pairs) ---
  k_rhist   <<<RB,  BS, 0, stream>>>(dst, E, histD, bktBase, NBK, ctrl);
  k_cursors <<<NBK, BS, 0, stream>>>(histD, bktBase, cursorTab, NBK);
  k_rscatter<<<RB,  BS, 0, stream>>>(dst, src, E, cursorTab, pairs, NBK);
  k_bplace2 <<<NBK, BS, 0, stream>>>(bktBase, pairs, rowptrD, colD, N, E);

  // --- FWI = [feat@W | permuted] interleaved fp8 ---
  k_fw      <<<2048, BS, 0, stream>>>(feat, Wenc, FWI, N);
  k_permrows<<<4096, BS, 0, stream>>>((unsigned*)FWI, permneg, N);

  // --- both perms: fused dual-perm pull BFS (interleaved hop12) + keep mask ---
  k_init2<<<NB, BS, 0, stream>>>(hop12, N, perm1, perm2, ctrl, bits1, bits2, WORDS);
  for(int it=0; it<MAXIT; it++)
    k_pullF<<<NB, BS, 0, stream>>>(rowptrD, colD, hop12, perm1, perm2, ctrl, it, N, target);
  k_flagscan2<<<2*NB, BS, 0, stream>>>(hop12, perm1, perm2, bits1, bits2,
                                       wordpref1, wordpref2, N, WORDS, ctrl, target, NB);
  k_keep2    <<<2*NB, BS, 0, stream>>>(hop12, perm1, perm2, bits1, bits2,
                                       wordpref1, wordpref2, keepPk, N, ctrl, target);

  // --- fused gather: pos/neg rows + both subgraph summaries in one CSR pass ---
  k_mega  <<<SUBB, BS, 0, stream>>>(rowptrD, colD, (const unsigned char*)FWI, keepPk,
                                    P, Q, sp1, sp2, N);
  k_redsum<<<R1B, BS, 0, stream>>>(sp1, sp2, SUBB, R1ROWS, sp1b, sp2b, Wdisc, cf, ctrl,
                                   1.f/(float)target);

  // --- streaming loss + final ---
  k_loss2<<<NB, BS, 0, stream>>>(P, Q, cf, ctrl, out, N);
}